// Round 8
// baseline (14.896 us; speedup 1.0000x reference)
//
#include <hip/hip_runtime.h>

#define RWIN 5
#define TMAX 8192

// One block per row, 640 threads = 10 waves = 2 waves per window (halves the
// straggler-row critical path vs 5-wave R6). R6's proven load structure:
// pre-issued <=4 independent float4 loads per wave (one waitcnt), masking
// only on the 2 edge iterations. Cross-wave pair combine in LDS, then a
// 10-element rank sort. Single launch, no atomics.
__global__ __launch_bounds__(640) void minmax_sort_kernel(
    const float* __restrict__ in, const int* __restrict__ lengths,
    float* __restrict__ out)
{
    __shared__ float smx[2 * RWIN];
    __shared__ float smn[2 * RWIN];
    __shared__ float vals[2 * RWIN];

    const int b    = blockIdx.x;
    const int tid  = threadIdx.x;     // 0..639
    const int win  = tid >> 7;        // window 0..4 (128-thread team)
    const int t2   = tid & 127;       // lane within team
    const int wid  = tid >> 6;        // wave 0..9
    const int lane = tid & 63;

    const int L = lengths[b];
    const float* rowp = in + (size_t)b * TMAX;

    const int s  = (win * L) / RWIN;                      // start (incl)
    const int e  = ((win + 1) * L + (RWIN - 1)) / RWIN;   // end (excl), >= s+1
    const int sa = s & ~3;                                // aligned start
    const int niter = (e - sa + 511) >> 9;                // 1..4 iters of 512

    const float NINF = -__builtin_inff();
    const float PINF =  __builtin_inff();
    const int t0 = sa + t2 * 4;

    // Pre-issue all loads back-to-back (tail lanes clamp to sa: aligned, in-row).
    float4 v[4];
    #pragma unroll
    for (int i = 0; i < 4; ++i) {
        if (i < niter) {
            const int t = t0 + (i << 9);
            v[i] = *reinterpret_cast<const float4*>(rowp + (t < e ? t : sa));
        }
    }

    // Reduce: interior iterations fully inside [s,e); edges masked per element.
    float mx = NINF, mn = PINF;
    #pragma unroll
    for (int i = 0; i < 4; ++i) {
        if (i < niter) {
            if (i > 0 && i < niter - 1) {
                mx = fmaxf(mx, fmaxf(fmaxf(v[i].x, v[i].y), fmaxf(v[i].z, v[i].w)));
                mn = fminf(mn, fminf(fminf(v[i].x, v[i].y), fminf(v[i].z, v[i].w)));
            } else {
                const int t = t0 + (i << 9);
                const float xs[4] = {v[i].x, v[i].y, v[i].z, v[i].w};
                #pragma unroll
                for (int j = 0; j < 4; ++j) {
                    const int  idx = t + j;
                    const bool ok  = (idx >= s) & (idx < e);
                    mx = fmaxf(mx, ok ? xs[j] : NINF);
                    mn = fminf(mn, ok ? xs[j] : PINF);
                }
            }
        }
    }

    // Wave butterfly, then pairwise cross-wave combine via LDS.
    #pragma unroll
    for (int off = 1; off < 64; off <<= 1) {
        mx = fmaxf(mx, __shfl_xor(mx, off));
        mn = fminf(mn, __shfl_xor(mn, off));
    }
    if (lane == 0) { smx[wid] = mx; smn[wid] = mn; }
    __syncthreads();

    if (tid < RWIN) {
        vals[tid] = fmaxf(smx[2 * tid], smx[2 * tid + 1]);
    } else if (tid < 2 * RWIN) {
        const int k = tid - RWIN;
        vals[tid] = fminf(smn[2 * k], smn[2 * k + 1]);
    }
    __syncthreads();

    // Rank sort of the 10 values (stable via index tie-break); ascending.
    if (tid < 2 * RWIN) {
        const float vv = vals[tid];
        int pos = 0;
        #pragma unroll
        for (int j = 0; j < 2 * RWIN; ++j) {
            const float vj = vals[j];
            pos += (int)((vj < vv) | ((vj == vv) & (j < tid)));
        }
        out[b * (2 * RWIN) + pos] = vv;
    }
}

extern "C" void kernel_launch(void* const* d_in, const int* in_sizes, int n_in,
                              void* d_out, int out_size, void* d_ws, size_t ws_size,
                              hipStream_t stream) {
    const float* in      = (const float*)d_in[0];
    const int*   lengths = (const int*)d_in[1];
    float*       out     = (float*)d_out;
    const int B = in_sizes[1];   // 2048 rows
    minmax_sort_kernel<<<B, 640, 0, stream>>>(in, lengths, out);
}

// Round 10
// 11.512 us; speedup vs baseline: 1.2939x; 1.2939x over previous
//
#include <hip/hip_runtime.h>

#define RWIN 5
#define TMAX 8192

typedef float f32x4 __attribute__((ext_vector_type(4)));

// R6 winner (best measured: 11.3 us) + nontemporal streaming loads.
// One block per row, 320 threads = 5 waves, wave w owns window
// w = [floor(w*L/5), ceil((w+1)*L/5)). All <=7 float4 loads per wave are
// pre-issued into registers (independent clamped addresses -> back-to-back
// issue, one waitcnt), masking only on the 2 edge iterations. Wave butterfly,
// one barrier, 10-element rank sort. Single launch, no atomics.
__global__ __launch_bounds__(5 * 64) void minmax_sort_kernel(
    const float* __restrict__ in, const int* __restrict__ lengths,
    float* __restrict__ out)
{
    __shared__ float sm[2 * RWIN];

    const int b    = blockIdx.x;
    const int tid  = threadIdx.x;
    const int w    = tid >> 6;    // window 0..4
    const int lane = tid & 63;

    const int L = lengths[b];
    const float* rowp = in + (size_t)b * TMAX;

    const int s  = (w * L) / RWIN;                      // start (incl)
    const int e  = ((w + 1) * L + (RWIN - 1)) / RWIN;   // end (excl), >= s+1
    const int sa = s & ~3;                              // aligned start
    const int niter = (e - sa + 255) >> 8;              // 1..7 iters of 256 elems

    const float NINF = -__builtin_inff();
    const float PINF =  __builtin_inff();
    const int t0 = sa + lane * 4;

    // Pass 1: pre-issue all loads back-to-back, nontemporal (read-once stream;
    // tail lanes clamp to sa, which is aligned and in-row).
    f32x4 v[7];
    #pragma unroll
    for (int i = 0; i < 7; ++i) {
        if (i < niter) {
            const int t = t0 + (i << 8);
            v[i] = __builtin_nontemporal_load(
                reinterpret_cast<const f32x4*>(rowp + (t < e ? t : sa)));
        }
    }

    // Pass 2: reduce. Interior iterations are fully inside [s,e); only the
    // first and last iteration need per-element masks.
    float mx = NINF, mn = PINF;
    #pragma unroll
    for (int i = 0; i < 7; ++i) {
        if (i < niter) {
            if (i > 0 && i < niter - 1) {
                mx = fmaxf(mx, fmaxf(fmaxf(v[i][0], v[i][1]), fmaxf(v[i][2], v[i][3])));
                mn = fminf(mn, fminf(fminf(v[i][0], v[i][1]), fminf(v[i][2], v[i][3])));
            } else {
                const int t = t0 + (i << 8);
                #pragma unroll
                for (int j = 0; j < 4; ++j) {
                    const int  idx = t + j;
                    const bool ok  = (idx >= s) & (idx < e);
                    mx = fmaxf(mx, ok ? v[i][j] : NINF);
                    mn = fminf(mn, ok ? v[i][j] : PINF);
                }
            }
        }
    }

    // Wave-level butterfly reduction (64 lanes).
    #pragma unroll
    for (int off = 1; off < 64; off <<= 1) {
        mx = fmaxf(mx, __shfl_xor(mx, off));
        mn = fminf(mn, __shfl_xor(mn, off));
    }
    if (lane == 0) { sm[w] = mx; sm[RWIN + w] = mn; }
    __syncthreads();

    // Rank sort of the 10 values (stable via index tie-break); ascending.
    if (tid < 2 * RWIN) {
        const float vv = sm[tid];
        int pos = 0;
        #pragma unroll
        for (int j = 0; j < 2 * RWIN; ++j) {
            const float vj = sm[j];
            pos += (int)((vj < vv) | ((vj == vv) & (j < tid)));
        }
        out[b * (2 * RWIN) + pos] = vv;
    }
}

extern "C" void kernel_launch(void* const* d_in, const int* in_sizes, int n_in,
                              void* d_out, int out_size, void* d_ws, size_t ws_size,
                              hipStream_t stream) {
    const float* in      = (const float*)d_in[0];
    const int*   lengths = (const int*)d_in[1];
    float*       out     = (float*)d_out;
    const int B = in_sizes[1];   // 2048 rows
    minmax_sort_kernel<<<B, 5 * 64, 0, stream>>>(in, lengths, out);
}